// Round 1
// baseline (277.345 us; speedup 1.0000x reference)
//
#include <hip/hip_runtime.h>
#include <hip/hip_bf16.h>

#define B_ 2
#define S_ 2048
#define D_ 1024
#define H_ 16
#define HD_ 64

typedef __attribute__((ext_vector_type(8))) short short8;
typedef __attribute__((ext_vector_type(4))) float f32x4;

static __device__ __forceinline__ ushort f2bf(float x) {
  __hip_bfloat16 h = __float2bfloat16(x);
  return *reinterpret_cast<ushort*>(&h);
}

static __device__ __forceinline__ void gld_lds16(void* lds, const void* g) {
  __builtin_amdgcn_global_load_lds(
      (__attribute__((address_space(1))) void*)(g),
      (__attribute__((address_space(3))) void*)(lds), 16, 0, 0);
}

// ---------------- conversion kernels ----------------

__global__ __launch_bounds__(256) void cvt_bf16_vec(const float4* __restrict__ in,
                                                    ushort* __restrict__ out, int n4) {
  int i = blockIdx.x * blockDim.x + threadIdx.x;
  if (i < n4) {
    float4 v = in[i];
    ushort4 o;
    o.x = f2bf(v.x); o.y = f2bf(v.y); o.z = f2bf(v.z); o.w = f2bf(v.w);
    *reinterpret_cast<ushort4*>(out + (size_t)i * 4) = o;
  }
}

// in: [K][N] f32 row-major  ->  out: [N][K] bf16 row-major
__global__ __launch_bounds__(256) void transpose_cvt(const float* __restrict__ in,
                                                     ushort* __restrict__ out,
                                                     int K, int N) {
  __shared__ float tile[32][33];
  const int bn = blockIdx.x * 32, bk = blockIdx.y * 32;
  const int tx = threadIdx.x, ty = threadIdx.y;
  #pragma unroll
  for (int i = ty; i < 32; i += 8)
    tile[i][tx] = in[(size_t)(bk + i) * N + bn + tx];
  __syncthreads();
  #pragma unroll
  for (int i = ty; i < 32; i += 8)
    out[(size_t)(bn + i) * K + bk + tx] = f2bf(tile[tx][i]);
}

// ---------------- GEMM: C = A @ Bt^T + bias ----------------
// A  : [M][K] bf16 row-major
// Bt : [N][K] bf16 row-major (i.e. B transposed)
// out row-major [M][N]; OUT_BF16 ? bf16 : f32
template <bool OUT_BF16>
__global__ __launch_bounds__(256) void gemm_bt(const ushort* __restrict__ A,
                                               const ushort* __restrict__ Bt,
                                               const float* __restrict__ bias,
                                               ushort* __restrict__ Cb,
                                               float* __restrict__ Cf,
                                               int M, int N, int K) {
  __shared__ __align__(16) ushort As[128 * 32];
  __shared__ __align__(16) ushort Bs[128 * 32];
  const int tid = threadIdx.x;
  const int lane = tid & 63, wid = tid >> 6;
  const int wr = wid >> 1, wc = wid & 1;
  const int row0 = blockIdx.x * 128, col0 = blockIdx.y * 128;
  const int l15 = lane & 15, lhi = lane >> 4;

  f32x4 acc[4][4];
  #pragma unroll
  for (int i = 0; i < 4; ++i)
    #pragma unroll
    for (int j = 0; j < 4; ++j)
      acc[i][j] = f32x4{0.f, 0.f, 0.f, 0.f};

  const int sr = tid >> 2;          // staging row 0..63 (per half)
  const int scol = (tid & 3) * 8;   // staging k offset

  for (int k0 = 0; k0 < K; k0 += 32) {
    gld_lds16(&As[(size_t)tid * 8],        &A[(size_t)(row0 + sr) * K + k0 + scol]);
    gld_lds16(&As[2048 + (size_t)tid * 8], &A[(size_t)(row0 + 64 + sr) * K + k0 + scol]);
    gld_lds16(&Bs[(size_t)tid * 8],        &Bt[(size_t)(col0 + sr) * K + k0 + scol]);
    gld_lds16(&Bs[2048 + (size_t)tid * 8], &Bt[(size_t)(col0 + 64 + sr) * K + k0 + scol]);
    __syncthreads();

    short8 af[4], bfr[4];
    #pragma unroll
    for (int mt = 0; mt < 4; ++mt)
      af[mt] = *(const short8*)&As[(wr * 64 + mt * 16 + l15) * 32 + lhi * 8];
    #pragma unroll
    for (int nt = 0; nt < 4; ++nt)
      bfr[nt] = *(const short8*)&Bs[(wc * 64 + nt * 16 + l15) * 32 + lhi * 8];
    #pragma unroll
    for (int mt = 0; mt < 4; ++mt)
      #pragma unroll
      for (int nt = 0; nt < 4; ++nt)
        acc[mt][nt] = __builtin_amdgcn_mfma_f32_16x16x32_bf16(af[mt], bfr[nt], acc[mt][nt], 0, 0, 0);
    __syncthreads();
  }

  const int orow = row0 + wr * 64;
  const int ocol = col0 + wc * 64 + l15;
  #pragma unroll
  for (int mt = 0; mt < 4; ++mt) {
    #pragma unroll
    for (int nt = 0; nt < 4; ++nt) {
      const int gc = ocol + nt * 16;
      const float bv = bias[gc];
      #pragma unroll
      for (int r = 0; r < 4; ++r) {
        const int gr = orow + mt * 16 + lhi * 4 + r;
        const float v = acc[mt][nt][r] + bv;
        if (OUT_BF16) Cb[(size_t)gr * N + gc] = f2bf(v);
        else          Cf[(size_t)gr * N + gc] = v;
      }
    }
  }
}

// ---------------- flash attention ----------------
// qkv   : [B][S][3072] bf16 ; head h: q at h*192, k at h*192+64, v at h*192+128
// mask  : [B][S][S] f32 additive
// values: [B*H][S][64] bf16  (contiguous == reference reshape order)
__global__ __launch_bounds__(256) void flash_attn(const ushort* __restrict__ qkv,
                                                  const float* __restrict__ mask,
                                                  ushort* __restrict__ values) {
  __shared__ __align__(16) ushort Ks[64 * 64];
  __shared__ __align__(16) ushort Vt[64 * 64];
  __shared__ __align__(16) ushort Ps[4][16 * 64];

  const int tid = threadIdx.x;
  const int lane = tid & 63, wid = tid >> 6;
  const int qt = blockIdx.x;
  const int bh = blockIdx.y, b = bh >> 4, h = bh & 15;
  const size_t base = (size_t)b * S_ * 3072 + (size_t)h * 192;
  const int q0 = qt * 64 + wid * 16;
  const int l15 = lane & 15, lhi = lane >> 4;

  // Q fragments (A-operand): row=lane&15, k=(lane>>4)*8 (+32 for second chunk)
  short8 qf[2];
  {
    const ushort* qrow = qkv + base + (size_t)(q0 + l15) * 3072 + lhi * 8;
    qf[0] = *(const short8*)qrow;
    qf[1] = *(const short8*)(qrow + 32);
  }

  float m_run[4], l_run[4];
  f32x4 o_acc[4];
  #pragma unroll
  for (int r = 0; r < 4; ++r) { m_run[r] = -3.0e38f; l_run[r] = 0.f; }
  #pragma unroll
  for (int dt = 0; dt < 4; ++dt) o_acc[dt] = f32x4{0.f, 0.f, 0.f, 0.f};

  const int krow = tid >> 3;        // 0..31
  const int kcol = (tid & 7) * 8;   // 0..56

  for (int kt = 0; kt < S_ / 64; ++kt) {
    const int kbase = kt * 64;
    // K tile -> LDS (row-major [64 keys][64 d]), async direct-to-LDS
    gld_lds16(&Ks[(size_t)tid * 8],        qkv + base + (size_t)(kbase + krow) * 3072 + 64 + kcol);
    gld_lds16(&Ks[2048 + (size_t)tid * 8], qkv + base + (size_t)(kbase + 32 + krow) * 3072 + 64 + kcol);
    // V tile -> LDS transposed [64 d][64 keys] via register scatter
    #pragma unroll
    for (int j = 0; j < 2; ++j) {
      const int r = j * 32 + krow;
      short8 v = *(const short8*)(qkv + base + (size_t)(kbase + r) * 3072 + 128 + kcol);
      #pragma unroll
      for (int x = 0; x < 8; ++x) Vt[(kcol + x) * 64 + r] = (ushort)v[x];
    }
    __syncthreads();

    // scores: 4 sub-tiles of 16 keys; lane holds rows lhi*4+r, col=key l15
    float sc[4][4];
    #pragma unroll
    for (int k16 = 0; k16 < 4; ++k16) {
      f32x4 s = f32x4{0.f, 0.f, 0.f, 0.f};
      const ushort* kp = &Ks[(k16 * 16 + l15) * 64 + lhi * 8];
      s = __builtin_amdgcn_mfma_f32_16x16x32_bf16(qf[0], *(const short8*)kp, s, 0, 0, 0);
      s = __builtin_amdgcn_mfma_f32_16x16x32_bf16(qf[1], *(const short8*)(kp + 32), s, 0, 0, 0);
      const int key = kbase + k16 * 16 + l15;
      const float* mrow = mask + ((size_t)b * S_ + q0 + lhi * 4) * S_ + key;
      #pragma unroll
      for (int r = 0; r < 4; ++r)
        sc[k16][r] = s[r] * 0.125f + mrow[(size_t)r * S_];
    }

    // online softmax, per q-row (stats replicated across the 16-lane group)
    #pragma unroll
    for (int r = 0; r < 4; ++r) {
      float mx = fmaxf(fmaxf(sc[0][r], sc[1][r]), fmaxf(sc[2][r], sc[3][r]));
      mx = fmaxf(mx, __shfl_xor(mx, 1, 16));
      mx = fmaxf(mx, __shfl_xor(mx, 2, 16));
      mx = fmaxf(mx, __shfl_xor(mx, 4, 16));
      mx = fmaxf(mx, __shfl_xor(mx, 8, 16));
      const float mnew = fmaxf(m_run[r], mx);
      const float alpha = __expf(m_run[r] - mnew);
      float ps = 0.f;
      #pragma unroll
      for (int k16 = 0; k16 < 4; ++k16) {
        const float p = __expf(sc[k16][r] - mnew);
        sc[k16][r] = p;
        ps += p;
      }
      ps += __shfl_xor(ps, 1, 16);
      ps += __shfl_xor(ps, 2, 16);
      ps += __shfl_xor(ps, 4, 16);
      ps += __shfl_xor(ps, 8, 16);
      l_run[r] = l_run[r] * alpha + ps;
      m_run[r] = mnew;
      #pragma unroll
      for (int dt = 0; dt < 4; ++dt) o_acc[dt][r] *= alpha;
    }

    // P (bf16) -> LDS in A-fragment-consumable layout [16 rows][64 keys]
    ushort* pw = &Ps[wid][0];
    #pragma unroll
    for (int k16 = 0; k16 < 4; ++k16)
      #pragma unroll
      for (int r = 0; r < 4; ++r)
        pw[(lhi * 4 + r) * 64 + k16 * 16 + l15] = f2bf(sc[k16][r]);

    // PV: A=P[16x64], B=V^T rows; accumulate into o_acc
    short8 pa0 = *(const short8*)&pw[l15 * 64 + lhi * 8];
    short8 pa1 = *(const short8*)&pw[l15 * 64 + 32 + lhi * 8];
    #pragma unroll
    for (int dt = 0; dt < 4; ++dt) {
      const ushort* vp = &Vt[(dt * 16 + l15) * 64 + lhi * 8];
      o_acc[dt] = __builtin_amdgcn_mfma_f32_16x16x32_bf16(pa0, *(const short8*)vp, o_acc[dt], 0, 0, 0);
      o_acc[dt] = __builtin_amdgcn_mfma_f32_16x16x32_bf16(pa1, *(const short8*)(vp + 32), o_acc[dt], 0, 0, 0);
    }
    __syncthreads();
  }

  #pragma unroll
  for (int r = 0; r < 4; ++r) {
    const float inv = 1.0f / l_run[r];
    const size_t vrow = ((size_t)bh * S_ + q0 + lhi * 4 + r) * 64;
    #pragma unroll
    for (int dt = 0; dt < 4; ++dt)
      values[vrow + dt * 16 + l15] = f2bf(o_acc[dt][r] * inv);
  }
}

// ---------------- launch ----------------

extern "C" void kernel_launch(void* const* d_in, const int* in_sizes, int n_in,
                              void* d_out, int out_size, void* d_ws, size_t ws_size,
                              hipStream_t stream) {
  const float* x    = (const float*)d_in[0];
  const float* mask = (const float*)d_in[1];
  const float* Wqkv = (const float*)d_in[2];
  const float* bqkv = (const float*)d_in[3];
  const float* Wo   = (const float*)d_in[4];
  const float* bo   = (const float*)d_in[5];
  float* out = (float*)d_out;

  char* ws = (char*)d_ws;
  // layout (bytes):
  //   [0, 8388608)        x_bf, later aliased by values (stream-ordered safe)
  //   [8388608, 14680064) WqkvT bf16 [3072][1024]
  //   [14680064,16777216) WoT   bf16 [1024][1024]
  //   [16777216,41943040) qkv   bf16 [4096][3072]
  ushort* xbf    = (ushort*)(ws + 0);
  ushort* vals   = (ushort*)(ws + 0);
  ushort* wqkvT  = (ushort*)(ws + 8388608);
  ushort* woT    = (ushort*)(ws + 14680064);
  ushort* qkv    = (ushort*)(ws + 16777216);

  // x -> bf16
  cvt_bf16_vec<<<4096, 256, 0, stream>>>((const float4*)x, xbf, (B_ * S_ * D_) / 4);
  // Wqkv^T, Wo^T -> bf16
  transpose_cvt<<<dim3(3 * D_ / 32, D_ / 32), dim3(32, 8), 0, stream>>>(Wqkv, wqkvT, D_, 3 * D_);
  transpose_cvt<<<dim3(D_ / 32, D_ / 32), dim3(32, 8), 0, stream>>>(Wo, woT, D_, D_);
  // qkv = x @ Wqkv + bqkv   (bf16 out)
  gemm_bt<true><<<dim3((B_ * S_) / 128, (3 * D_) / 128), 256, 0, stream>>>(
      xbf, wqkvT, bqkv, qkv, nullptr, B_ * S_, 3 * D_, D_);
  // flash attention -> values [B*H][S][64] (aliases x_bf region; x_bf is dead here)
  flash_attn<<<dim3(S_ / 64, B_ * H_), 256, 0, stream>>>(qkv, mask, vals);
  // out = values @ Wo + bo  (f32 out)
  gemm_bt<false><<<dim3((B_ * S_) / 128, D_ / 128), 256, 0, stream>>>(
      vals, woT, bo, nullptr, out, B_ * S_, D_, D_);
}

// Round 2
// 235.958 us; speedup vs baseline: 1.1754x; 1.1754x over previous
//
#include <hip/hip_runtime.h>
#include <hip/hip_bf16.h>

#define B_ 2
#define S_ 2048
#define D_ 1024
#define H_ 16
#define HD_ 64

typedef __attribute__((ext_vector_type(8))) short short8;
typedef __attribute__((ext_vector_type(4))) float f32x4;

static __device__ __forceinline__ ushort f2bf(float x) {
  __hip_bfloat16 h = __float2bfloat16(x);
  return *reinterpret_cast<ushort*>(&h);
}

static __device__ __forceinline__ void gld_lds16(void* lds, const void* g) {
  __builtin_amdgcn_global_load_lds(
      (__attribute__((address_space(1))) void*)(g),
      (__attribute__((address_space(3))) void*)(lds), 16, 0, 0);
}

// ---------------- conversion kernels ----------------

__global__ __launch_bounds__(256) void cvt_bf16_vec(const float4* __restrict__ in,
                                                    ushort* __restrict__ out, int n4) {
  int i = blockIdx.x * blockDim.x + threadIdx.x;
  if (i < n4) {
    float4 v = in[i];
    ushort4 o;
    o.x = f2bf(v.x); o.y = f2bf(v.y); o.z = f2bf(v.z); o.w = f2bf(v.w);
    *reinterpret_cast<ushort4*>(out + (size_t)i * 4) = o;
  }
}

// in: [K][N] f32 row-major  ->  out: [N][K] bf16 row-major
__global__ __launch_bounds__(256) void transpose_cvt(const float* __restrict__ in,
                                                     ushort* __restrict__ out,
                                                     int K, int N) {
  __shared__ float tile[32][33];
  const int bn = blockIdx.x * 32, bk = blockIdx.y * 32;
  const int tx = threadIdx.x, ty = threadIdx.y;
  #pragma unroll
  for (int i = ty; i < 32; i += 8)
    tile[i][tx] = in[(size_t)(bk + i) * N + bn + tx];
  __syncthreads();
  #pragma unroll
  for (int i = ty; i < 32; i += 8)
    out[(size_t)(bn + i) * K + bk + tx] = f2bf(tile[tx][i]);
}

// ---------------- GEMM: C = A @ Bt^T + bias ----------------
template <bool OUT_BF16>
__global__ __launch_bounds__(256) void gemm_bt(const ushort* __restrict__ A,
                                               const ushort* __restrict__ Bt,
                                               const float* __restrict__ bias,
                                               ushort* __restrict__ Cb,
                                               float* __restrict__ Cf,
                                               int M, int N, int K) {
  __shared__ __align__(16) ushort As[128 * 32];
  __shared__ __align__(16) ushort Bs[128 * 32];
  const int tid = threadIdx.x;
  const int lane = tid & 63, wid = tid >> 6;
  const int wr = wid >> 1, wc = wid & 1;
  const int row0 = blockIdx.x * 128, col0 = blockIdx.y * 128;
  const int l15 = lane & 15, lhi = lane >> 4;

  f32x4 acc[4][4];
  #pragma unroll
  for (int i = 0; i < 4; ++i)
    #pragma unroll
    for (int j = 0; j < 4; ++j)
      acc[i][j] = f32x4{0.f, 0.f, 0.f, 0.f};

  const int sr = tid >> 2;
  const int scol = (tid & 3) * 8;

  for (int k0 = 0; k0 < K; k0 += 32) {
    gld_lds16(&As[(size_t)tid * 8],        &A[(size_t)(row0 + sr) * K + k0 + scol]);
    gld_lds16(&As[2048 + (size_t)tid * 8], &A[(size_t)(row0 + 64 + sr) * K + k0 + scol]);
    gld_lds16(&Bs[(size_t)tid * 8],        &Bt[(size_t)(col0 + sr) * K + k0 + scol]);
    gld_lds16(&Bs[2048 + (size_t)tid * 8], &Bt[(size_t)(col0 + 64 + sr) * K + k0 + scol]);
    __syncthreads();

    short8 af[4], bfr[4];
    #pragma unroll
    for (int mt = 0; mt < 4; ++mt)
      af[mt] = *(const short8*)&As[(wr * 64 + mt * 16 + l15) * 32 + lhi * 8];
    #pragma unroll
    for (int nt = 0; nt < 4; ++nt)
      bfr[nt] = *(const short8*)&Bs[(wc * 64 + nt * 16 + l15) * 32 + lhi * 8];
    #pragma unroll
    for (int mt = 0; mt < 4; ++mt)
      #pragma unroll
      for (int nt = 0; nt < 4; ++nt)
        acc[mt][nt] = __builtin_amdgcn_mfma_f32_16x16x32_bf16(af[mt], bfr[nt], acc[mt][nt], 0, 0, 0);
    __syncthreads();
  }

  const int orow = row0 + wr * 64;
  const int ocol = col0 + wc * 64 + l15;
  #pragma unroll
  for (int mt = 0; mt < 4; ++mt) {
    #pragma unroll
    for (int nt = 0; nt < 4; ++nt) {
      const int gc = ocol + nt * 16;
      const float bv = bias[gc];
      #pragma unroll
      for (int r = 0; r < 4; ++r) {
        const int gr = orow + mt * 16 + lhi * 4 + r;
        const float v = acc[mt][nt][r] + bv;
        if (OUT_BF16) Cb[(size_t)gr * N + gc] = f2bf(v);
        else          Cf[(size_t)gr * N + gc] = v;
      }
    }
  }
}

// ---------------- flash attention (swizzled LDS, double-buffered) ----------------
// Swizzle: within each 128-byte LDS row, 16B-chunk index c is stored at
// c ^ h(row), h(row) = (row ^ (row>>3)) & 7.  Applied to Ks (k-rows),
// Vt (d-rows, k contiguous) and Ps (q-rows).
__global__ __launch_bounds__(256) void flash_attn(const ushort* __restrict__ qkv,
                                                  const float* __restrict__ mask,
                                                  ushort* __restrict__ values) {
  __shared__ __align__(16) ushort Ks[2][64 * 64];
  __shared__ __align__(16) ushort Vt[2][64 * 64];
  __shared__ __align__(16) ushort Ps[4][16 * 64];

  const int tid = threadIdx.x;
  const int lane = tid & 63, wid = tid >> 6;
  const int qt = blockIdx.x;
  const int bh = blockIdx.y, b = bh >> 4, h = bh & 15;
  const size_t base = (size_t)b * S_ * 3072 + (size_t)h * 192;
  const int q0 = qt * 64 + wid * 16;
  const int l15 = lane & 15, lhi = lane >> 4;

  // Q fragments (A-operand): row=lane&15, k=(lane>>4)*8 (+32 second chunk)
  short8 qf[2];
  {
    const ushort* qrow = qkv + base + (size_t)(q0 + l15) * 3072 + lhi * 8;
    qf[0] = *(const short8*)qrow;
    qf[1] = *(const short8*)(qrow + 32);
  }

  // staging decomposition: 256 threads cover 32 rows x 8 chunks (16B each)
  const int srow = tid >> 3;        // 0..31
  const int sch  = tid & 7;         // chunk 0..7
  const int hA   = ((srow >> 3) ^ srow) & 7;        // h(srow)
  const int scA  = sch ^ hA;                        // swizzled src chunk, rows 0..31
  const int scB  = sch ^ (hA ^ 4);                  // rows 32..63 (row>>3 += 4)
  const int kcol = sch * 8;                         // V: this thread's 8 d-values

  float m_run[4], l_run[4];
  f32x4 o_acc[4];
  #pragma unroll
  for (int r = 0; r < 4; ++r) { m_run[r] = -3.0e38f; l_run[r] = 0.f; }
  #pragma unroll
  for (int dt = 0; dt < 4; ++dt) o_acc[dt] = f32x4{0.f, 0.f, 0.f, 0.f};

  const float* mbase = mask + ((size_t)b * S_ + q0 + lhi * 4) * S_;
  float mk[4][4], mkn[4][4];   // [k16][r] current / next tile mask

  const int NT = S_ / 64;
  int cur = 0;

  // ---- prologue: stage tile 0 ----
  {
    const ushort* kg = qkv + base + (size_t)srow * 3072;
    gld_lds16(&Ks[0][tid * 8],        kg + 64 + scA * 8);
    gld_lds16(&Ks[0][2048 + tid * 8], kg + (size_t)32 * 3072 + 64 + scB * 8);
    short8 v0 = *(const short8*)(kg + 128 + kcol);
    short8 v1 = *(const short8*)(kg + (size_t)32 * 3072 + 128 + kcol);
    #pragma unroll
    for (int k16 = 0; k16 < 4; ++k16)
      #pragma unroll
      for (int r = 0; r < 4; ++r)
        mk[k16][r] = mbase[(size_t)r * S_ + k16 * 16 + l15];
    #pragma unroll
    for (int x = 0; x < 8; ++x) {
      const int d = kcol + x;
      const int hd = (x ^ sch) & 7;                 // h(d)
      Vt[0][d * 64 + ((( srow >> 3)      ^ hd) & 7) * 8 + (srow & 7)] = (ushort)v0[x];
      Vt[0][d * 64 + ((((srow >> 3) + 4) ^ hd) & 7) * 8 + (srow & 7)] = (ushort)v1[x];
    }
    __syncthreads();
  }

  for (int kt = 0; kt < NT; ++kt) {
    const int nxt = cur ^ 1;
    const bool pre = (kt + 1 < NT);
    short8 v0, v1;
    if (pre) {
      const size_t nb = base + (size_t)(kt + 1) * 64 * 3072;
      const ushort* kg = qkv + nb + (size_t)srow * 3072;
      gld_lds16(&Ks[nxt][tid * 8],        kg + 64 + scA * 8);
      gld_lds16(&Ks[nxt][2048 + tid * 8], kg + (size_t)32 * 3072 + 64 + scB * 8);
      v0 = *(const short8*)(kg + 128 + kcol);
      v1 = *(const short8*)(kg + (size_t)32 * 3072 + 128 + kcol);
      const float* mn = mbase + (size_t)(kt + 1) * 64;
      #pragma unroll
      for (int k16 = 0; k16 < 4; ++k16)
        #pragma unroll
        for (int r = 0; r < 4; ++r)
          mkn[k16][r] = mn[(size_t)r * S_ + k16 * 16 + l15];
    }

    // ---- QK^T ----
    float sc[4][4];
    __builtin_amdgcn_s_setprio(1);
    #pragma unroll
    for (int k16 = 0; k16 < 4; ++k16) {
      const int row = k16 * 16 + l15;
      const int hk = ((row >> 3) ^ row) & 7;
      const ushort* kp = &Ks[cur][row * 64];
      f32x4 s = f32x4{0.f, 0.f, 0.f, 0.f};
      s = __builtin_amdgcn_mfma_f32_16x16x32_bf16(qf[0], *(const short8*)&kp[((lhi     ^ hk) & 7) * 8], s, 0, 0, 0);
      s = __builtin_amdgcn_mfma_f32_16x16x32_bf16(qf[1], *(const short8*)&kp[(((lhi+4) ^ hk) & 7) * 8], s, 0, 0, 0);
      #pragma unroll
      for (int r = 0; r < 4; ++r)
        sc[k16][r] = s[r] * 0.125f + mk[k16][r];
    }
    __builtin_amdgcn_s_setprio(0);

    // ---- online softmax (stats replicated across 16-lane group) ----
    #pragma unroll
    for (int r = 0; r < 4; ++r) {
      float mx = fmaxf(fmaxf(sc[0][r], sc[1][r]), fmaxf(sc[2][r], sc[3][r]));
      mx = fmaxf(mx, __shfl_xor(mx, 1, 16));
      mx = fmaxf(mx, __shfl_xor(mx, 2, 16));
      mx = fmaxf(mx, __shfl_xor(mx, 4, 16));
      mx = fmaxf(mx, __shfl_xor(mx, 8, 16));
      const float mnew = fmaxf(m_run[r], mx);
      const float alpha = __expf(m_run[r] - mnew);
      float ps = 0.f;
      #pragma unroll
      for (int k16 = 0; k16 < 4; ++k16) {
        const float p = __expf(sc[k16][r] - mnew);
        sc[k16][r] = p;
        ps += p;
      }
      ps += __shfl_xor(ps, 1, 16);
      ps += __shfl_xor(ps, 2, 16);
      ps += __shfl_xor(ps, 4, 16);
      ps += __shfl_xor(ps, 8, 16);
      l_run[r] = l_run[r] * alpha + ps;
      m_run[r] = mnew;
      #pragma unroll
      for (int dt = 0; dt < 4; ++dt) o_acc[dt][r] *= alpha;
    }

    // ---- P -> LDS (swizzled), same-wave consumption ----
    ushort* pw = &Ps[wid][0];
    #pragma unroll
    for (int k16 = 0; k16 < 4; ++k16)
      #pragma unroll
      for (int r = 0; r < 4; ++r) {
        const int q = lhi * 4 + r;
        const int swz = ((k16 * 2 + (l15 >> 3)) ^ ((q >> 3) ^ q)) & 7;
        pw[q * 64 + swz * 8 + (l15 & 7)] = f2bf(sc[k16][r]);
      }

    // ---- PV ----
    short8 pa0, pa1;
    {
      const int hp = ((l15 >> 3) ^ l15) & 7;
      const ushort* prow = &Ps[wid][l15 * 64];
      pa0 = *(const short8*)&prow[((lhi     ^ hp) & 7) * 8];
      pa1 = *(const short8*)&prow[(((lhi+4) ^ hp) & 7) * 8];
    }
    __builtin_amdgcn_s_setprio(1);
    #pragma unroll
    for (int dt = 0; dt < 4; ++dt) {
      const int dr = dt * 16 + l15;
      const int hv = ((dr >> 3) ^ dr) & 7;
      const ushort* vp = &Vt[cur][dr * 64];
      o_acc[dt] = __builtin_amdgcn_mfma_f32_16x16x32_bf16(pa0, *(const short8*)&vp[((lhi     ^ hv) & 7) * 8], o_acc[dt], 0, 0, 0);
      o_acc[dt] = __builtin_amdgcn_mfma_f32_16x16x32_bf16(pa1, *(const short8*)&vp[(((lhi+4) ^ hv) & 7) * 8], o_acc[dt], 0, 0, 0);
    }
    __builtin_amdgcn_s_setprio(0);

    // ---- late V scatter into next buffer (T14 split) ----
    if (pre) {
      #pragma unroll
      for (int x = 0; x < 8; ++x) {
        const int d = kcol + x;
        const int hd = (x ^ sch) & 7;
        Vt[nxt][d * 64 + ((( srow >> 3)      ^ hd) & 7) * 8 + (srow & 7)] = (ushort)v0[x];
        Vt[nxt][d * 64 + ((((srow >> 3) + 4) ^ hd) & 7) * 8 + (srow & 7)] = (ushort)v1[x];
      }
      #pragma unroll
      for (int k16 = 0; k16 < 4; ++k16)
        #pragma unroll
        for (int r = 0; r < 4; ++r)
          mk[k16][r] = mkn[k16][r];
    }
    __syncthreads();
    cur = nxt;
  }

  #pragma unroll
  for (int r = 0; r < 4; ++r) {
    const float inv = 1.0f / l_run[r];
    const size_t vrow = ((size_t)bh * S_ + q0 + lhi * 4 + r) * 64;
    #pragma unroll
    for (int dt = 0; dt < 4; ++dt)
      values[vrow + dt * 16 + l15] = f2bf(o_acc[dt][r] * inv);
  }
}

// ---------------- launch ----------------

extern "C" void kernel_launch(void* const* d_in, const int* in_sizes, int n_in,
                              void* d_out, int out_size, void* d_ws, size_t ws_size,
                              hipStream_t stream) {
  const float* x    = (const float*)d_in[0];
  const float* mask = (const float*)d_in[1];
  const float* Wqkv = (const float*)d_in[2];
  const float* bqkv = (const float*)d_in[3];
  const float* Wo   = (const float*)d_in[4];
  const float* bo   = (const float*)d_in[5];
  float* out = (float*)d_out;

  char* ws = (char*)d_ws;
  ushort* xbf    = (ushort*)(ws + 0);
  ushort* vals   = (ushort*)(ws + 0);
  ushort* wqkvT  = (ushort*)(ws + 8388608);
  ushort* woT    = (ushort*)(ws + 14680064);
  ushort* qkv    = (ushort*)(ws + 16777216);

  cvt_bf16_vec<<<4096, 256, 0, stream>>>((const float4*)x, xbf, (B_ * S_ * D_) / 4);
  transpose_cvt<<<dim3(3 * D_ / 32, D_ / 32), dim3(32, 8), 0, stream>>>(Wqkv, wqkvT, D_, 3 * D_);
  transpose_cvt<<<dim3(D_ / 32, D_ / 32), dim3(32, 8), 0, stream>>>(Wo, woT, D_, D_);
  gemm_bt<true><<<dim3((B_ * S_) / 128, (3 * D_) / 128), 256, 0, stream>>>(
      xbf, wqkvT, bqkv, qkv, nullptr, B_ * S_, 3 * D_, D_);
  flash_attn<<<dim3(S_ / 64, B_ * H_), 256, 0, stream>>>(qkv, mask, vals);
  gemm_bt<false><<<dim3((B_ * S_) / 128, D_ / 128), 256, 0, stream>>>(
      vals, woT, bo, nullptr, out, B_ * S_, D_, D_);
}

// Round 3
// 215.556 us; speedup vs baseline: 1.2866x; 1.0946x over previous
//
#include <hip/hip_runtime.h>
#include <hip/hip_bf16.h>

#define B_ 2
#define S_ 2048
#define D_ 1024
#define H_ 16
#define HD_ 64

typedef __attribute__((ext_vector_type(8))) short short8;
typedef __attribute__((ext_vector_type(4))) float f32x4;
typedef __attribute__((ext_vector_type(4))) unsigned short us4;

static __device__ __forceinline__ ushort f2bf(float x) {
  __hip_bfloat16 h = __float2bfloat16(x);
  return *reinterpret_cast<ushort*>(&h);
}

static __device__ __forceinline__ void gld_lds16(void* lds, const void* g) {
  __builtin_amdgcn_global_load_lds(
      (__attribute__((address_space(1))) void*)(g),
      (__attribute__((address_space(3))) void*)(lds), 16, 0, 0);
}

// ---------------- conversion kernels ----------------

__global__ __launch_bounds__(256) void cvt_bf16_vec(const float4* __restrict__ in,
                                                    ushort* __restrict__ out, int n4) {
  int i = blockIdx.x * blockDim.x + threadIdx.x;
  if (i < n4) {
    float4 v = in[i];
    ushort4 o;
    o.x = f2bf(v.x); o.y = f2bf(v.y); o.z = f2bf(v.z); o.w = f2bf(v.w);
    *reinterpret_cast<ushort4*>(out + (size_t)i * 4) = o;
  }
}

// in: [K][N] f32 row-major  ->  out: [N][K] bf16 row-major
__global__ __launch_bounds__(256) void transpose_cvt(const float* __restrict__ in,
                                                     ushort* __restrict__ out,
                                                     int K, int N) {
  __shared__ float tile[32][33];
  const int bn = blockIdx.x * 32, bk = blockIdx.y * 32;
  const int tx = threadIdx.x, ty = threadIdx.y;
  #pragma unroll
  for (int i = ty; i < 32; i += 8)
    tile[i][tx] = in[(size_t)(bk + i) * N + bn + tx];
  __syncthreads();
  #pragma unroll
  for (int i = ty; i < 32; i += 8)
    out[(size_t)(bn + i) * K + bk + tx] = f2bf(tile[tx][i]);
}

// ---------------- GEMM: C = A @ Bt^T + bias ----------------
template <bool OUT_BF16>
__global__ __launch_bounds__(256) void gemm_bt(const ushort* __restrict__ A,
                                               const ushort* __restrict__ Bt,
                                               const float* __restrict__ bias,
                                               ushort* __restrict__ Cb,
                                               float* __restrict__ Cf,
                                               int M, int N, int K) {
  __shared__ __align__(16) ushort As[128 * 32];
  __shared__ __align__(16) ushort Bs[128 * 32];
  const int tid = threadIdx.x;
  const int lane = tid & 63, wid = tid >> 6;
  const int wr = wid >> 1, wc = wid & 1;
  const int row0 = blockIdx.x * 128, col0 = blockIdx.y * 128;
  const int l15 = lane & 15, lhi = lane >> 4;

  f32x4 acc[4][4];
  #pragma unroll
  for (int i = 0; i < 4; ++i)
    #pragma unroll
    for (int j = 0; j < 4; ++j)
      acc[i][j] = f32x4{0.f, 0.f, 0.f, 0.f};

  const int sr = tid >> 2;
  const int scol = (tid & 3) * 8;

  for (int k0 = 0; k0 < K; k0 += 32) {
    gld_lds16(&As[(size_t)tid * 8],        &A[(size_t)(row0 + sr) * K + k0 + scol]);
    gld_lds16(&As[2048 + (size_t)tid * 8], &A[(size_t)(row0 + 64 + sr) * K + k0 + scol]);
    gld_lds16(&Bs[(size_t)tid * 8],        &Bt[(size_t)(col0 + sr) * K + k0 + scol]);
    gld_lds16(&Bs[2048 + (size_t)tid * 8], &Bt[(size_t)(col0 + 64 + sr) * K + k0 + scol]);
    __syncthreads();

    short8 af[4], bfr[4];
    #pragma unroll
    for (int mt = 0; mt < 4; ++mt)
      af[mt] = *(const short8*)&As[(wr * 64 + mt * 16 + l15) * 32 + lhi * 8];
    #pragma unroll
    for (int nt = 0; nt < 4; ++nt)
      bfr[nt] = *(const short8*)&Bs[(wc * 64 + nt * 16 + l15) * 32 + lhi * 8];
    #pragma unroll
    for (int mt = 0; mt < 4; ++mt)
      #pragma unroll
      for (int nt = 0; nt < 4; ++nt)
        acc[mt][nt] = __builtin_amdgcn_mfma_f32_16x16x32_bf16(af[mt], bfr[nt], acc[mt][nt], 0, 0, 0);
    __syncthreads();
  }

  const int orow = row0 + wr * 64;
  const int ocol = col0 + wc * 64 + l15;
  #pragma unroll
  for (int mt = 0; mt < 4; ++mt) {
    #pragma unroll
    for (int nt = 0; nt < 4; ++nt) {
      const int gc = ocol + nt * 16;
      const float bv = bias[gc];
      #pragma unroll
      for (int r = 0; r < 4; ++r) {
        const int gr = orow + mt * 16 + lhi * 4 + r;
        const float v = acc[mt][nt][r] + bv;
        if (OUT_BF16) Cb[(size_t)gr * N + gc] = f2bf(v);
        else          Cf[(size_t)gr * N + gc] = v;
      }
    }
  }
}

// ---------------- flash attention, swapped-operand (register softmax) ----------------
// Per wave: 16 q-rows (q = q0 + l15). S^T = mfma(A=K, B=Q) with PERMUTED K rows
// so that each lane's score registers are exactly the PV B-fragment:
//   QK mfma m (m = c*2+half): A-row rho holds key c*32 + (rho>>2)*8 + half*4 + (rho&3)
//   => sc[m][r] = S^T[key = c*32 + lhi*8 + half*4 + r][q = l15]
//   => PV B-frag for key chunk c = pack(sc[2c][0..3], sc[2c+1][0..3])  (no cross-lane!)
// PV: O^T = mfma(A=V^T, B=P^T), V^T staged in LDS with XOR swizzle.
// LDS swizzles (16B-chunk index XOR):  K: h(row) = (row&3)|((row&8)>>1);  V: h(row)=row&7.
__global__ __launch_bounds__(256, 4) void flash_attn(const ushort* __restrict__ qkv,
                                                     const float* __restrict__ mask,
                                                     ushort* __restrict__ values) {
  __shared__ __align__(16) ushort Ks[2][64 * 64];
  __shared__ __align__(16) ushort Vt[2][64 * 64];

  const int tid = threadIdx.x;
  const int lane = tid & 63, wid = tid >> 6;
  const int l15 = lane & 15, lhi = lane >> 4;
  const int qt = blockIdx.x, bh = blockIdx.y, b = bh >> 4, h = bh & 15;
  const size_t base = (size_t)b * S_ * 3072 + (size_t)h * 192;
  const int q = qt * 64 + wid * 16 + l15;

  // Q B-frag: Q[q][lhi*8+j] and Q[q][32+lhi*8+j]
  short8 qf0, qf1;
  {
    const ushort* qrow = qkv + base + (size_t)q * 3072 + lhi * 8;
    qf0 = *(const short8*)qrow;
    qf1 = *(const short8*)(qrow + 32);
  }

  // K staging: thread -> (srow 0..31, chunk sch 0..7); source chunk pre-swizzled
  const int srow = tid >> 3, sch = tid & 7;
  const int scs = sch ^ ((srow & 3) | ((srow & 8) >> 1));
  // V staging: thread -> 4 keys (kg*4..+3) x 4 d (d0..+3)
  const int kg = tid & 15, d0 = (tid >> 4) * 4;
  // QK read-side swizzle term (row bits of the permuted K row, independent of m)
  const int hkr = (l15 & 3) | (((l15 >> 2) & 1) << 2);
  // A-row -> permuted base row (bits from l15 only)
  const int klbase = ((l15 >> 2) << 3) | (l15 & 3);

  float m_run = -3.0e38f, l_run = 0.f;
  f32x4 o[4];
  #pragma unroll
  for (int dt = 0; dt < 4; ++dt) o[dt] = f32x4{0.f, 0.f, 0.f, 0.f};

  const float* mrow = mask + ((size_t)b * S_ + q) * S_;
  const int NT = S_ / 64;
  int cur = 0;
  us4 vr[4];

  // ---- prologue: stage tile 0 ----
  {
    const ushort* kg0 = qkv + base + (size_t)srow * 3072 + 64;
    gld_lds16(&Ks[0][tid * 8],        kg0 + scs * 8);
    gld_lds16(&Ks[0][2048 + tid * 8], kg0 + (size_t)32 * 3072 + scs * 8);
    #pragma unroll
    for (int kk = 0; kk < 4; ++kk)
      vr[kk] = *(const us4*)(qkv + base + (size_t)(kg * 4 + kk) * 3072 + 128 + d0);
    #pragma unroll
    for (int dd = 0; dd < 3 + 1; ++dd) {
      const int d = d0 + dd;
      us4 w;
      w[0] = vr[0][dd]; w[1] = vr[1][dd]; w[2] = vr[2][dd]; w[3] = vr[3][dd];
      *(us4*)&Vt[0][d * 64 + (((kg >> 1) ^ (d & 7)) * 8) + (kg & 1) * 4] = w;
    }
    __syncthreads();
  }

  for (int kt = 0; kt < NT; ++kt) {
    const int nxt = cur ^ 1;
    const bool pre = (kt + 1 < NT);

    // ---- early: issue next-tile K gld_lds + V register loads ----
    if (pre) {
      const ushort* kgn = qkv + base + (size_t)(kt + 1) * 64 * 3072 + (size_t)srow * 3072 + 64;
      gld_lds16(&Ks[nxt][tid * 8],        kgn + scs * 8);
      gld_lds16(&Ks[nxt][2048 + tid * 8], kgn + (size_t)32 * 3072 + scs * 8);
      #pragma unroll
      for (int kk = 0; kk < 4; ++kk)
        vr[kk] = *(const us4*)(qkv + base + (size_t)(kt + 1) * 64 * 3072 +
                               (size_t)(kg * 4 + kk) * 3072 + 128 + d0);
    }

    // ---- mask for current tile (4 x float4, per-lane row q) ----
    f32x4 mk[4];
    {
      const float* mp = mrow + kt * 64 + lhi * 8;
      mk[0] = *(const f32x4*)(mp);
      mk[1] = *(const f32x4*)(mp + 4);
      mk[2] = *(const f32x4*)(mp + 32);
      mk[3] = *(const f32x4*)(mp + 36);
    }

    // ---- QK^T (permuted K rows) ----
    f32x4 sc[4];
    __builtin_amdgcn_s_setprio(1);
    #pragma unroll
    for (int m = 0; m < 4; ++m) {
      const int kl = (m >> 1) * 32 + (m & 1) * 4 + klbase;   // permuted LDS row
      const int c1 = (lhi ^ hkr) & 7;
      const ushort* kp = &Ks[cur][kl * 64];
      short8 kf0 = *(const short8*)&kp[c1 * 8];
      short8 kf1 = *(const short8*)&kp[(c1 ^ 4) * 8];
      f32x4 s = f32x4{0.f, 0.f, 0.f, 0.f};
      s = __builtin_amdgcn_mfma_f32_16x16x32_bf16(kf0, qf0, s, 0, 0, 0);
      s = __builtin_amdgcn_mfma_f32_16x16x32_bf16(kf1, qf1, s, 0, 0, 0);
      sc[m] = s;
    }
    __builtin_amdgcn_s_setprio(0);

    // ---- scale + mask ----
    #pragma unroll
    for (int m = 0; m < 4; ++m)
      #pragma unroll
      for (int r = 0; r < 4; ++r)
        sc[m][r] = sc[m][r] * 0.125f + mk[m][r];

    // ---- softmax (per-lane q; combine 4 lhi groups with 2 shfls) ----
    float mx = sc[0][0];
    #pragma unroll
    for (int m = 0; m < 4; ++m)
      #pragma unroll
      for (int r = 0; r < 4; ++r) mx = fmaxf(mx, sc[m][r]);
    mx = fmaxf(mx, __shfl_xor(mx, 16));
    mx = fmaxf(mx, __shfl_xor(mx, 32));
    const float mnew = fmaxf(m_run, mx);
    const float alpha = __expf(m_run - mnew);
    m_run = mnew;
    float ps = 0.f;
    #pragma unroll
    for (int m = 0; m < 4; ++m)
      #pragma unroll
      for (int r = 0; r < 4; ++r) {
        const float p = __expf(sc[m][r] - mnew);
        sc[m][r] = p;
        ps += p;
      }
    ps += __shfl_xor(ps, 16);
    ps += __shfl_xor(ps, 32);
    l_run = l_run * alpha + ps;
    #pragma unroll
    for (int dt = 0; dt < 4; ++dt)
      #pragma unroll
      for (int r = 0; r < 4; ++r) o[dt][r] *= alpha;

    // ---- P fragments (pure in-register) ----
    short8 pf[2];
    #pragma unroll
    for (int c = 0; c < 2; ++c)
      #pragma unroll
      for (int j = 0; j < 8; ++j)
        pf[c][j] = (short)f2bf(sc[c * 2 + (j >> 2)][j & 3]);

    // ---- PV: O^T += V^T @ P^T ----
    __builtin_amdgcn_s_setprio(1);
    #pragma unroll
    for (int dt = 0; dt < 4; ++dt) {
      const int d = dt * 16 + l15;
      const ushort* vp = &Vt[cur][d * 64];
      #pragma unroll
      for (int c = 0; c < 2; ++c) {
        short8 vf = *(const short8*)&vp[(((c * 4 + lhi) ^ (d & 7)) & 7) * 8];
        o[dt] = __builtin_amdgcn_mfma_f32_16x16x32_bf16(vf, pf[c], o[dt], 0, 0, 0);
      }
    }
    __builtin_amdgcn_s_setprio(0);

    // ---- late: V register-transpose -> Vt[nxt] (4 x ds_write_b64) ----
    if (pre) {
      #pragma unroll
      for (int dd = 0; dd < 4; ++dd) {
        const int d = d0 + dd;
        us4 w;
        w[0] = vr[0][dd]; w[1] = vr[1][dd]; w[2] = vr[2][dd]; w[3] = vr[3][dd];
        *(us4*)&Vt[nxt][d * 64 + (((kg >> 1) ^ (d & 7)) * 8) + (kg & 1) * 4] = w;
      }
    }
    __syncthreads();
    cur = nxt;
  }

  // ---- epilogue: O^T/l -> values[bh][q][d], 4 x ushort4 stores ----
  const float inv = 1.0f / l_run;
  ushort* vout = values + ((size_t)bh * S_ + q) * 64 + lhi * 4;
  #pragma unroll
  for (int dt = 0; dt < 4; ++dt) {
    us4 w;
    #pragma unroll
    for (int r = 0; r < 4; ++r) w[r] = f2bf(o[dt][r] * inv);
    *(us4*)(vout + dt * 16) = w;
  }
}

// ---------------- launch ----------------

extern "C" void kernel_launch(void* const* d_in, const int* in_sizes, int n_in,
                              void* d_out, int out_size, void* d_ws, size_t ws_size,
                              hipStream_t stream) {
  const float* x    = (const float*)d_in[0];
  const float* mask = (const float*)d_in[1];
  const float* Wqkv = (const float*)d_in[2];
  const float* bqkv = (const float*)d_in[3];
  const float* Wo   = (const float*)d_in[4];
  const float* bo   = (const float*)d_in[5];
  float* out = (float*)d_out;

  char* ws = (char*)d_ws;
  ushort* xbf    = (ushort*)(ws + 0);
  ushort* vals   = (ushort*)(ws + 0);
  ushort* wqkvT  = (ushort*)(ws + 8388608);
  ushort* woT    = (ushort*)(ws + 14680064);
  ushort* qkv    = (ushort*)(ws + 16777216);

  cvt_bf16_vec<<<4096, 256, 0, stream>>>((const float4*)x, xbf, (B_ * S_ * D_) / 4);
  transpose_cvt<<<dim3(3 * D_ / 32, D_ / 32), dim3(32, 8), 0, stream>>>(Wqkv, wqkvT, D_, 3 * D_);
  transpose_cvt<<<dim3(D_ / 32, D_ / 32), dim3(32, 8), 0, stream>>>(Wo, woT, D_, D_);
  gemm_bt<true><<<dim3((B_ * S_) / 128, (3 * D_) / 128), 256, 0, stream>>>(
      xbf, wqkvT, bqkv, qkv, nullptr, B_ * S_, 3 * D_, D_);
  flash_attn<<<dim3(S_ / 64, B_ * H_), 256, 0, stream>>>(qkv, mask, vals);
  gemm_bt<false><<<dim3((B_ * S_) / 128, D_ / 128), 256, 0, stream>>>(
      vals, woT, bo, nullptr, out, B_ * S_, D_, D_);
}

// Round 4
// 180.432 us; speedup vs baseline: 1.5371x; 1.1947x over previous
//
#include <hip/hip_runtime.h>
#include <hip/hip_bf16.h>

#define B_ 2
#define S_ 2048
#define D_ 1024
#define H_ 16
#define HD_ 64

typedef __attribute__((ext_vector_type(8))) short short8;
typedef __attribute__((ext_vector_type(4))) float f32x4;
typedef __attribute__((ext_vector_type(16))) float f32x16;
typedef __attribute__((ext_vector_type(4))) unsigned short us4;

static __device__ __forceinline__ ushort f2bf(float x) {
  __hip_bfloat16 h = __float2bfloat16(x);
  return *reinterpret_cast<ushort*>(&h);
}

static __device__ __forceinline__ void gld_lds16(void* lds, const void* g) {
  __builtin_amdgcn_global_load_lds(
      (__attribute__((address_space(1))) void*)(g),
      (__attribute__((address_space(3))) void*)(lds), 16, 0, 0);
}

// ---------------- conversion kernels ----------------

__global__ __launch_bounds__(256) void cvt_bf16_vec(const float4* __restrict__ in,
                                                    ushort* __restrict__ out, int n4) {
  int i = blockIdx.x * blockDim.x + threadIdx.x;
  if (i < n4) {
    float4 v = in[i];
    ushort4 o;
    o.x = f2bf(v.x); o.y = f2bf(v.y); o.z = f2bf(v.z); o.w = f2bf(v.w);
    *reinterpret_cast<ushort4*>(out + (size_t)i * 4) = o;
  }
}

// in: [K][N] f32 row-major  ->  out: [N][K] bf16 row-major
__global__ __launch_bounds__(256) void transpose_cvt(const float* __restrict__ in,
                                                     ushort* __restrict__ out,
                                                     int K, int N) {
  __shared__ float tile[32][33];
  const int bn = blockIdx.x * 32, bk = blockIdx.y * 32;
  const int tx = threadIdx.x, ty = threadIdx.y;
  #pragma unroll
  for (int i = ty; i < 32; i += 8)
    tile[i][tx] = in[(size_t)(bk + i) * N + bn + tx];
  __syncthreads();
  #pragma unroll
  for (int i = ty; i < 32; i += 8)
    out[(size_t)(bn + i) * K + bk + tx] = f2bf(tile[tx][i]);
}

// ---------------- GEMM: C = A @ Bt^T + bias ----------------
template <bool OUT_BF16>
__global__ __launch_bounds__(256) void gemm_bt(const ushort* __restrict__ A,
                                               const ushort* __restrict__ Bt,
                                               const float* __restrict__ bias,
                                               ushort* __restrict__ Cb,
                                               float* __restrict__ Cf,
                                               int M, int N, int K) {
  __shared__ __align__(16) ushort As[128 * 32];
  __shared__ __align__(16) ushort Bs[128 * 32];
  const int tid = threadIdx.x;
  const int lane = tid & 63, wid = tid >> 6;
  const int wr = wid >> 1, wc = wid & 1;
  const int row0 = blockIdx.x * 128, col0 = blockIdx.y * 128;
  const int l15 = lane & 15, lhi = lane >> 4;

  f32x4 acc[4][4];
  #pragma unroll
  for (int i = 0; i < 4; ++i)
    #pragma unroll
    for (int j = 0; j < 4; ++j)
      acc[i][j] = f32x4{0.f, 0.f, 0.f, 0.f};

  const int sr = tid >> 2;
  const int scol = (tid & 3) * 8;

  for (int k0 = 0; k0 < K; k0 += 32) {
    gld_lds16(&As[(size_t)tid * 8],        &A[(size_t)(row0 + sr) * K + k0 + scol]);
    gld_lds16(&As[2048 + (size_t)tid * 8], &A[(size_t)(row0 + 64 + sr) * K + k0 + scol]);
    gld_lds16(&Bs[(size_t)tid * 8],        &Bt[(size_t)(col0 + sr) * K + k0 + scol]);
    gld_lds16(&Bs[2048 + (size_t)tid * 8], &Bt[(size_t)(col0 + 64 + sr) * K + k0 + scol]);
    __syncthreads();

    short8 af[4], bfr[4];
    #pragma unroll
    for (int mt = 0; mt < 4; ++mt)
      af[mt] = *(const short8*)&As[(wr * 64 + mt * 16 + l15) * 32 + lhi * 8];
    #pragma unroll
    for (int nt = 0; nt < 4; ++nt)
      bfr[nt] = *(const short8*)&Bs[(wc * 64 + nt * 16 + l15) * 32 + lhi * 8];
    #pragma unroll
    for (int mt = 0; mt < 4; ++mt)
      #pragma unroll
      for (int nt = 0; nt < 4; ++nt)
        acc[mt][nt] = __builtin_amdgcn_mfma_f32_16x16x32_bf16(af[mt], bfr[nt], acc[mt][nt], 0, 0, 0);
    __syncthreads();
  }

  const int orow = row0 + wr * 64;
  const int ocol = col0 + wc * 64 + l15;
  #pragma unroll
  for (int mt = 0; mt < 4; ++mt) {
    #pragma unroll
    for (int nt = 0; nt < 4; ++nt) {
      const int gc = ocol + nt * 16;
      const float bv = bias[gc];
      #pragma unroll
      for (int r = 0; r < 4; ++r) {
        const int gr = orow + mt * 16 + lhi * 4 + r;
        const float v = acc[mt][nt][r] + bv;
        if (OUT_BF16) Cb[(size_t)gr * N + gc] = f2bf(v);
        else          Cf[(size_t)gr * N + gc] = v;
      }
    }
  }
}

// ---------------- flash attention, 32x32 MFMA, 32 q-rows per wave ----------------
// S^T = mfma_32x32x16(A=K, B=Q): lane owns q = lane&31; score reg r of group g is
//   key = g*32 + (r&3) + 8*(r>>2) + 4*(lane>>5).
// PV k-axis permuted by pi = swap-bits-2-and-3 of key (involution): V^T stored with
// pi-relabeled columns, so the PV B-frag for kdepth ks is sc[ks>>1][8*(ks&1)+j] --
// pure in-register, no cross-lane movement. Sum over keys is permutation-invariant.
// LDS 16B-chunk XOR swizzle: h(row) = (row ^ (row>>3)) & 7 on K and V^T tiles.
__global__ __launch_bounds__(256, 2) void flash_attn(const ushort* __restrict__ qkv,
                                                     const float* __restrict__ mask,
                                                     ushort* __restrict__ values) {
  __shared__ __align__(16) ushort Ks[2][64 * 64];
  __shared__ __align__(16) ushort Vt[2][64 * 64];

  const int tid = threadIdx.x;
  const int lane = tid & 63, wid = tid >> 6;
  const int l31 = lane & 31, lhalf = lane >> 5;
  const int qt = blockIdx.x, bh = blockIdx.y, b = bh >> 4, h = bh & 15;
  const size_t base = (size_t)b * S_ * 3072 + (size_t)h * 192;
  const int q = qt * 128 + wid * 32 + l31;

  // Q B-frags: qf[kd] = Q[q][kd*16 + lhalf*8 + 0..7]
  short8 qf[4];
  {
    const ushort* qrow = qkv + base + (size_t)q * 3072 + lhalf * 8;
    qf[0] = *(const short8*)(qrow);
    qf[1] = *(const short8*)(qrow + 16);
    qf[2] = *(const short8*)(qrow + 32);
    qf[3] = *(const short8*)(qrow + 48);
  }

  // K staging (gld_lds, pre-swizzled source): rows 0..31 + rows 32..63
  const int srow = tid >> 3, sch = tid & 7;
  const int hsr = (srow ^ (srow >> 3)) & 7;
  const int scs = sch ^ hsr;                 // second half uses scs^4
  // V staging: thread owns keys kg*4..+3, d d0..d0+3; column relabel sigma(kg)
  const int kg = tid & 15, d0 = (tid >> 4) * 4;
  const int skg = (kg & 12) | ((kg & 1) << 1) | ((kg >> 1) & 1);

  float m_run = -3.0e38f, l_run = 0.f;
  f32x16 o[2];
  #pragma unroll
  for (int dg = 0; dg < 2; ++dg)
    #pragma unroll
    for (int i = 0; i < 16; ++i) o[dg][i] = 0.f;

  const float* mrow = mask + ((size_t)b * S_ + q) * S_;
  f32x4 mk[8], mkn[8];
  const int NT = S_ / 64;
  int cur = 0;
  us4 vr[4];

  // ---- prologue: stage tile 0 ----
  {
    const ushort* kgp = qkv + base + (size_t)srow * 3072 + 64;
    gld_lds16(&Ks[0][tid * 8],        kgp + scs * 8);
    gld_lds16(&Ks[0][2048 + tid * 8], kgp + (size_t)32 * 3072 + (scs ^ 4) * 8);
    #pragma unroll
    for (int kk = 0; kk < 4; ++kk)
      vr[kk] = *(const us4*)(qkv + base + (size_t)(kg * 4 + kk) * 3072 + 128 + d0);
    #pragma unroll
    for (int i = 0; i < 8; ++i)
      mk[i] = *(const f32x4*)(mrow + (i >> 2) * 32 + (i & 3) * 8 + lhalf * 4);
    #pragma unroll
    for (int dd = 0; dd < 4; ++dd) {
      const int d = d0 + dd;
      const int hd = (d ^ (d >> 3)) & 7;
      us4 w;
      w[0] = vr[0][dd]; w[1] = vr[1][dd]; w[2] = vr[2][dd]; w[3] = vr[3][dd];
      *(us4*)&Vt[0][d * 64 + (((skg >> 1) ^ hd) & 7) * 8 + (skg & 1) * 4] = w;
    }
    __syncthreads();
  }

  for (int kt = 0; kt < NT; ++kt) {
    const int nxt = cur ^ 1;
    const bool pre = (kt + 1 < NT);

    // ---- early: issue next-tile K gld_lds + V reg loads + mask prefetch ----
    if (pre) {
      const size_t nb = base + (size_t)(kt + 1) * 64 * 3072;
      const ushort* kgp = qkv + nb + (size_t)srow * 3072 + 64;
      gld_lds16(&Ks[nxt][tid * 8],        kgp + scs * 8);
      gld_lds16(&Ks[nxt][2048 + tid * 8], kgp + (size_t)32 * 3072 + (scs ^ 4) * 8);
      #pragma unroll
      for (int kk = 0; kk < 4; ++kk)
        vr[kk] = *(const us4*)(qkv + nb + (size_t)(kg * 4 + kk) * 3072 + 128 + d0);
      const float* mn = mrow + (size_t)(kt + 1) * 64;
      #pragma unroll
      for (int i = 0; i < 8; ++i)
        mkn[i] = *(const f32x4*)(mn + (i >> 2) * 32 + (i & 3) * 8 + lhalf * 4);
    }

    // ---- QK^T: sc[g][r] = S^T[key][q] ----
    f32x16 sc[2];
    __builtin_amdgcn_s_setprio(1);
    #pragma unroll
    for (int g = 0; g < 2; ++g) {
      const int row = g * 32 + l31;
      const int hk = (row ^ (row >> 3)) & 7;
      const ushort* kp = &Ks[cur][row * 64];
      f32x16 s;
      #pragma unroll
      for (int i = 0; i < 16; ++i) s[i] = 0.f;
      #pragma unroll
      for (int kd = 0; kd < 4; ++kd) {
        short8 kf = *(const short8*)&kp[(((kd * 2 + lhalf) ^ hk) & 7) * 8];
        s = __builtin_amdgcn_mfma_f32_32x32x16_bf16(kf, qf[kd], s, 0, 0, 0);
      }
      sc[g] = s;
    }
    __builtin_amdgcn_s_setprio(0);

    // ---- scale + mask ----
    #pragma unroll
    for (int g = 0; g < 2; ++g)
      #pragma unroll
      for (int r = 0; r < 16; ++r)
        sc[g][r] = sc[g][r] * 0.125f + mk[g * 4 + (r >> 2)][r & 3];

    // ---- online softmax (per-lane q; 1 shfl to combine lane-halves) ----
    float mx = sc[0][0];
    #pragma unroll
    for (int g = 0; g < 2; ++g)
      #pragma unroll
      for (int r = 0; r < 16; ++r) mx = fmaxf(mx, sc[g][r]);
    mx = fmaxf(mx, __shfl_xor(mx, 32));
    const float mnew = fmaxf(m_run, mx);
    const float alpha = __expf(m_run - mnew);
    m_run = mnew;
    float ps = 0.f;
    #pragma unroll
    for (int g = 0; g < 2; ++g)
      #pragma unroll
      for (int r = 0; r < 16; ++r) {
        const float p = __expf(sc[g][r] - mnew);
        sc[g][r] = p;
        ps += p;
      }
    ps += __shfl_xor(ps, 32);
    l_run = l_run * alpha + ps;
    #pragma unroll
    for (int dg = 0; dg < 2; ++dg)
      #pragma unroll
      for (int i = 0; i < 16; ++i) o[dg][i] *= alpha;

    // ---- P fragments: pi-permuted k-axis => my own regs, no shuffles ----
    short8 pf[4];
    #pragma unroll
    for (int ks = 0; ks < 4; ++ks)
      #pragma unroll
      for (int j = 0; j < 8; ++j)
        pf[ks][j] = (short)f2bf(sc[ks >> 1][8 * (ks & 1) + j]);

    // ---- PV: O^T += V^T(pi) @ P^T(pi) ----
    __builtin_amdgcn_s_setprio(1);
    #pragma unroll
    for (int dg = 0; dg < 2; ++dg) {
      const int d = dg * 32 + l31;
      const int hv = (d ^ (d >> 3)) & 7;
      const ushort* vp = &Vt[cur][d * 64];
      #pragma unroll
      for (int ks = 0; ks < 4; ++ks) {
        short8 vf = *(const short8*)&vp[(((ks * 2 + lhalf) ^ hv) & 7) * 8];
        o[dg] = __builtin_amdgcn_mfma_f32_32x32x16_bf16(vf, pf[ks], o[dg], 0, 0, 0);
      }
    }
    __builtin_amdgcn_s_setprio(0);

    // ---- late: V register-transpose into Vt[nxt] (sigma-relabeled cols) ----
    if (pre) {
      #pragma unroll
      for (int dd = 0; dd < 4; ++dd) {
        const int d = d0 + dd;
        const int hd = (d ^ (d >> 3)) & 7;
        us4 w;
        w[0] = vr[0][dd]; w[1] = vr[1][dd]; w[2] = vr[2][dd]; w[3] = vr[3][dd];
        *(us4*)&Vt[nxt][d * 64 + (((skg >> 1) ^ hd) & 7) * 8 + (skg & 1) * 4] = w;
      }
      #pragma unroll
      for (int i = 0; i < 8; ++i) mk[i] = mkn[i];
    }
    __syncthreads();
    cur = nxt;
  }

  // ---- epilogue: O^T/l -> values[bh][q][d] ----
  const float inv = 1.0f / l_run;
  ushort* vout = values + ((size_t)bh * S_ + q) * 64;
  #pragma unroll
  for (int dg = 0; dg < 2; ++dg)
    #pragma unroll
    for (int quad = 0; quad < 4; ++quad) {
      us4 w;
      #pragma unroll
      for (int r = 0; r < 4; ++r) w[r] = f2bf(o[dg][quad * 4 + r] * inv);
      *(us4*)(vout + dg * 32 + quad * 8 + lhalf * 4) = w;
    }
}

// ---------------- launch ----------------

extern "C" void kernel_launch(void* const* d_in, const int* in_sizes, int n_in,
                              void* d_out, int out_size, void* d_ws, size_t ws_size,
                              hipStream_t stream) {
  const float* x    = (const float*)d_in[0];
  const float* mask = (const float*)d_in[1];
  const float* Wqkv = (const float*)d_in[2];
  const float* bqkv = (const float*)d_in[3];
  const float* Wo   = (const float*)d_in[4];
  const float* bo   = (const float*)d_in[5];
  float* out = (float*)d_out;

  char* ws = (char*)d_ws;
  ushort* xbf    = (ushort*)(ws + 0);
  ushort* vals   = (ushort*)(ws + 0);
  ushort* wqkvT  = (ushort*)(ws + 8388608);
  ushort* woT    = (ushort*)(ws + 14680064);
  ushort* qkv    = (ushort*)(ws + 16777216);

  cvt_bf16_vec<<<4096, 256, 0, stream>>>((const float4*)x, xbf, (B_ * S_ * D_) / 4);
  transpose_cvt<<<dim3(3 * D_ / 32, D_ / 32), dim3(32, 8), 0, stream>>>(Wqkv, wqkvT, D_, 3 * D_);
  transpose_cvt<<<dim3(D_ / 32, D_ / 32), dim3(32, 8), 0, stream>>>(Wo, woT, D_, D_);
  gemm_bt<true><<<dim3((B_ * S_) / 128, (3 * D_) / 128), 256, 0, stream>>>(
      xbf, wqkvT, bqkv, qkv, nullptr, B_ * S_, 3 * D_, D_);
  flash_attn<<<dim3(S_ / 128, B_ * H_), 256, 0, stream>>>(qkv, mask, vals);
  gemm_bt<false><<<dim3((B_ * S_) / 128, D_ / 128), 256, 0, stream>>>(
      vals, woT, bo, nullptr, out, B_ * S_, D_, D_);
}